// Round 1
// baseline (8366.185 us; speedup 1.0000x reference)
//
#include <hip/hip_runtime.h>
#include <hip/hip_bf16.h>

#define N_NODES 100000
#define N_EDGES 1600000
#define DIM 128
#define N_LAYERS 3

// ---------------------------------------------------------------------------
// GEMM: H = X @ W   (X: [N,128], W: [128,128] row-major, H: [N,128])
// Block handles 16 rows x 64 cols. W-half (128x64 = 32KB) + 16 X rows staged
// in LDS. Xs padded to 129 floats/row to avoid 4-way bank conflict on the
// per-k broadcast read.
// ---------------------------------------------------------------------------
__global__ __launch_bounds__(256) void gemm128(const float* __restrict__ X,
                                               const float* __restrict__ W,
                                               float* __restrict__ H) {
  __shared__ float Ws[128 * 64];
  __shared__ float Xs[16][129];
  const int tid = threadIdx.x;
  const int bid = blockIdx.x;
  const int colBase = (bid & 1) * 64;
  const int row0 = (bid >> 1) * 16;

  // stage W columns [colBase, colBase+64): 128 k-rows x 16 float4
  for (int i = tid; i < 128 * 16; i += 256) {
    const int k = i >> 4, j = i & 15;
    ((float4*)Ws)[i] = *(const float4*)&W[k * 128 + colBase + j * 4];
  }
  // stage 16 X rows
  for (int i = tid; i < 16 * 32; i += 256) {
    const int r = i >> 5, j = i & 31;
    float4 v = *(const float4*)&X[(size_t)(row0 + r) * DIM + j * 4];
    Xs[r][j * 4 + 0] = v.x;
    Xs[r][j * 4 + 1] = v.y;
    Xs[r][j * 4 + 2] = v.z;
    Xs[r][j * 4 + 3] = v.w;
  }
  __syncthreads();

  const int g = tid >> 4;     // row within chunk (0..15)
  const int lane = tid & 15;  // 16 lanes x float4 = 64 cols
  float4 acc = {0.f, 0.f, 0.f, 0.f};
#pragma unroll 8
  for (int k = 0; k < 128; ++k) {
    const float xv = Xs[g][k];
    const float4 w = ((const float4*)Ws)[k * 16 + lane];
    acc.x += xv * w.x;
    acc.y += xv * w.y;
    acc.z += xv * w.z;
    acc.w += xv * w.w;
  }
  *(float4*)&H[(size_t)(row0 + g) * DIM + colBase + lane * 4] = acc;
}

// ---------------------------------------------------------------------------
// out[n][:] = bias[:]  (broadcast init; bias is 128 floats)
// one thread per float4; grid*block == N*DIM/4 exactly
// ---------------------------------------------------------------------------
__global__ __launch_bounds__(256) void init_bias(float* __restrict__ out,
                                                 const float* __restrict__ b) {
  const int i = blockIdx.x * 256 + threadIdx.x;  // float4 index
  const float4 bv = ((const float4*)b)[i & 31];  // 32 float4 per row
  ((float4*)out)[i] = bv;
}

// ---------------------------------------------------------------------------
// scatter: for each edge e: out[dst[e]][:] += h[src[e]][:] * w[e]
// 32 lanes per edge, float4 per lane, 4 scalar fp32 atomics.
// ---------------------------------------------------------------------------
__global__ __launch_bounds__(256) void scatter_edges(
    const float* __restrict__ H, const int* __restrict__ src,
    const int* __restrict__ dst, const float* __restrict__ w,
    float* __restrict__ out) {
  const int tid = threadIdx.x;
  const int e = blockIdx.x * 8 + (tid >> 5);
  const int lane = tid & 31;
  const int s = src[e];
  const int d = dst[e];
  const float wt = w[e];
  const float4 hv = *(const float4*)&H[(size_t)s * DIM + lane * 4];
  float* op = &out[(size_t)d * DIM + lane * 4];
  atomicAdd(op + 0, hv.x * wt);
  atomicAdd(op + 1, hv.y * wt);
  atomicAdd(op + 2, hv.z * wt);
  atomicAdd(op + 3, hv.w * wt);
}

// ---------------------------------------------------------------------------
// in-place ReLU over N*DIM floats (float4 per thread)
// ---------------------------------------------------------------------------
__global__ __launch_bounds__(256) void relu_k(float* __restrict__ o) {
  const int i = blockIdx.x * 256 + threadIdx.x;
  float4 v = ((float4*)o)[i];
  v.x = fmaxf(v.x, 0.f);
  v.y = fmaxf(v.y, 0.f);
  v.z = fmaxf(v.z, 0.f);
  v.w = fmaxf(v.w, 0.f);
  ((float4*)o)[i] = v;
}

extern "C" void kernel_launch(void* const* d_in, const int* in_sizes, int n_in,
                              void* d_out, int out_size, void* d_ws,
                              size_t ws_size, hipStream_t stream) {
  const float* x = (const float*)d_in[0];
  const int* esrc = (const int*)d_in[1];
  const int* edst = (const int*)d_in[2];
  const float* ew = (const float*)d_in[3];
  const float* W = (const float*)d_in[4];
  const float* b = (const float*)d_in[5];
  float* out = (float*)d_out;

  float* h_buf = (float*)d_ws;                        // [N, D] fp32
  float* act_buf = h_buf + (size_t)N_NODES * DIM;     // [N, D] fp32

  const int gemm_blocks = (N_NODES / 16) * 2;         // 12500
  const int vec_blocks = (N_NODES * DIM / 4) / 256;   // 12500
  const int scat_blocks = N_EDGES / 8;                // 200000

  const float* in = x;
  for (int l = 0; l < N_LAYERS; ++l) {
    float* o = (l == N_LAYERS - 1) ? out : act_buf;
    gemm128<<<gemm_blocks, 256, 0, stream>>>(in, W + (size_t)l * DIM * DIM,
                                             h_buf);
    init_bias<<<vec_blocks, 256, 0, stream>>>(o, b + (size_t)l * DIM);
    scatter_edges<<<scat_blocks, 256, 0, stream>>>(h_buf, esrc, edst, ew, o);
    relu_k<<<vec_blocks, 256, 0, stream>>>(o);
    in = o;  // layer 1 reads act_buf and rewrites it; stream-ordered, safe
  }
}

// Round 2
// 964.176 us; speedup vs baseline: 8.6770x; 8.6770x over previous
//
#include <hip/hip_runtime.h>
#include <hip/hip_bf16.h>

#define N_NODES 100000
#define N_EDGES 1600000
#define DIM 128
#define N_LAYERS 3

#define SCAN_T 1024
#define NB ((N_NODES + SCAN_T - 1) / SCAN_T)  // 98

// ---------------------------------------------------------------------------
// GEMM: H = X @ W   (X: [N,128], W: [128,128] row-major, H: [N,128])
// ---------------------------------------------------------------------------
__global__ __launch_bounds__(256) void gemm128(const float* __restrict__ X,
                                               const float* __restrict__ W,
                                               float* __restrict__ H) {
  __shared__ float Ws[128 * 64];
  __shared__ float Xs[16][129];
  const int tid = threadIdx.x;
  const int bid = blockIdx.x;
  const int colBase = (bid & 1) * 64;
  const int row0 = (bid >> 1) * 16;

  for (int i = tid; i < 128 * 16; i += 256) {
    const int k = i >> 4, j = i & 15;
    ((float4*)Ws)[i] = *(const float4*)&W[k * 128 + colBase + j * 4];
  }
  for (int i = tid; i < 16 * 32; i += 256) {
    const int r = i >> 5, j = i & 31;
    float4 v = *(const float4*)&X[(size_t)(row0 + r) * DIM + j * 4];
    Xs[r][j * 4 + 0] = v.x;
    Xs[r][j * 4 + 1] = v.y;
    Xs[r][j * 4 + 2] = v.z;
    Xs[r][j * 4 + 3] = v.w;
  }
  __syncthreads();

  const int g = tid >> 4;
  const int lane = tid & 15;
  float4 acc = {0.f, 0.f, 0.f, 0.f};
#pragma unroll 8
  for (int k = 0; k < 128; ++k) {
    const float xv = Xs[g][k];
    const float4 w = ((const float4*)Ws)[k * 16 + lane];
    acc.x += xv * w.x;
    acc.y += xv * w.y;
    acc.z += xv * w.z;
    acc.w += xv * w.w;
  }
  *(float4*)&H[(size_t)(row0 + g) * DIM + colBase + lane * 4] = acc;
}

// ---------------------------------------------------------------------------
// CSR build: histogram -> exclusive scan -> cursor fill
// ---------------------------------------------------------------------------
__global__ __launch_bounds__(256) void zero_cnt(int* __restrict__ cnt) {
  const int i = blockIdx.x * 256 + threadIdx.x;
  if (i < N_NODES) cnt[i] = 0;
}

__global__ __launch_bounds__(256) void hist_dst(const int* __restrict__ dst,
                                                int* __restrict__ cnt) {
  const int e = blockIdx.x * 256 + threadIdx.x;
  if (e < N_EDGES) atomicAdd(&cnt[dst[e]], 1);
}

__global__ __launch_bounds__(SCAN_T) void scan_reduce(
    const int* __restrict__ cnt, int* __restrict__ bsum) {
  __shared__ int sh[SCAN_T];
  const int i = blockIdx.x * SCAN_T + threadIdx.x;
  sh[threadIdx.x] = (i < N_NODES) ? cnt[i] : 0;
  __syncthreads();
  for (int off = SCAN_T / 2; off > 0; off >>= 1) {
    if (threadIdx.x < off) sh[threadIdx.x] += sh[threadIdx.x + off];
    __syncthreads();
  }
  if (threadIdx.x == 0) bsum[blockIdx.x] = sh[0];
}

__global__ __launch_bounds__(128) void scan_bsum(const int* __restrict__ bsum,
                                                 int* __restrict__ boff) {
  __shared__ int sh[128];
  const int t = threadIdx.x;
  const int v = (t < NB) ? bsum[t] : 0;
  sh[t] = v;
  __syncthreads();
  for (int off = 1; off < 128; off <<= 1) {
    int a = (t >= off) ? sh[t - off] : 0;
    __syncthreads();
    sh[t] += a;
    __syncthreads();
  }
  if (t < NB) boff[t] = sh[t] - v;  // exclusive
}

__global__ __launch_bounds__(SCAN_T) void scan_final(
    const int* __restrict__ cnt, const int* __restrict__ boff,
    int* __restrict__ row_ptr, int* __restrict__ cursor) {
  __shared__ int sh[SCAN_T];
  const int i = blockIdx.x * SCAN_T + threadIdx.x;
  const int v = (i < N_NODES) ? cnt[i] : 0;
  sh[threadIdx.x] = v;
  __syncthreads();
  for (int off = 1; off < SCAN_T; off <<= 1) {
    int a = (threadIdx.x >= off) ? sh[threadIdx.x - off] : 0;
    __syncthreads();
    sh[threadIdx.x] += a;
    __syncthreads();
  }
  const int ex = sh[threadIdx.x] - v + boff[blockIdx.x];
  if (i < N_NODES) {
    row_ptr[i] = ex;
    cursor[i] = ex;
  }
  if (i == 0) row_ptr[N_NODES] = N_EDGES;
}

__global__ __launch_bounds__(256) void fill_csr(
    const int* __restrict__ src, const int* __restrict__ dst,
    const float* __restrict__ ew, int* __restrict__ cursor,
    int* __restrict__ col, float* __restrict__ wv) {
  const int e = blockIdx.x * 256 + threadIdx.x;
  if (e >= N_EDGES) return;
  const int d = dst[e];
  const int pos = atomicAdd(&cursor[d], 1);
  col[pos] = src[e];
  wv[pos] = ew[e];
}

// ---------------------------------------------------------------------------
// aggregate: out[n][:] = relu( sum_{e in csr[n]} H[col[e]][:]*wv[e] + bias )
// one 64-lane wave per node, float2 per lane (128 cols)
// ---------------------------------------------------------------------------
__global__ __launch_bounds__(256) void aggregate(
    const float* __restrict__ H, const int* __restrict__ row_ptr,
    const int* __restrict__ col, const float* __restrict__ wv,
    const float* __restrict__ bias, float* __restrict__ out) {
  const int node = blockIdx.x * 4 + (threadIdx.x >> 6);
  const int lane = threadIdx.x & 63;
  if (node >= N_NODES) return;
  const int beg = row_ptr[node];
  const int end = row_ptr[node + 1];
  float2 acc = {0.f, 0.f};
  for (int i = beg; i < end; ++i) {
    const int s = col[i];
    const float w = wv[i];
    const float2 h = *(const float2*)&H[(size_t)s * DIM + lane * 2];
    acc.x += h.x * w;
    acc.y += h.y * w;
  }
  const float2 bv = *(const float2*)&bias[lane * 2];
  float2 o;
  o.x = fmaxf(acc.x + bv.x, 0.f);
  o.y = fmaxf(acc.y + bv.y, 0.f);
  *(float2*)&out[(size_t)node * DIM + lane * 2] = o;
}

extern "C" void kernel_launch(void* const* d_in, const int* in_sizes, int n_in,
                              void* d_out, int out_size, void* d_ws,
                              size_t ws_size, hipStream_t stream) {
  const float* x = (const float*)d_in[0];
  const int* esrc = (const int*)d_in[1];
  const int* edst = (const int*)d_in[2];
  const float* ew = (const float*)d_in[3];
  const float* W = (const float*)d_in[4];
  const float* b = (const float*)d_in[5];
  float* out = (float*)d_out;

  // workspace layout
  float* h_buf = (float*)d_ws;                         // [N*D] f32
  float* act_buf = h_buf + (size_t)N_NODES * DIM;      // [N*D] f32
  int* col = (int*)(act_buf + (size_t)N_NODES * DIM);  // [E]
  float* wv = (float*)(col + N_EDGES);                 // [E]
  int* cnt = (int*)(wv + N_EDGES);                     // [N]
  int* row_ptr = cnt + N_NODES;                        // [N+1]
  int* cursor = row_ptr + N_NODES + 1;                 // [N]
  int* bsum = cursor + N_NODES;                        // [NB]
  int* boff = bsum + NB;                               // [NB]

  const int nblk = (N_NODES + 255) / 256;   // 391
  const int eblk = (N_EDGES + 255) / 256;   // 6250

  // ---- CSR build (once, reused by all 3 layers) ----
  zero_cnt<<<nblk, 256, 0, stream>>>(cnt);
  hist_dst<<<eblk, 256, 0, stream>>>(edst, cnt);
  scan_reduce<<<NB, SCAN_T, 0, stream>>>(cnt, bsum);
  scan_bsum<<<1, 128, 0, stream>>>(bsum, boff);
  scan_final<<<NB, SCAN_T, 0, stream>>>(cnt, boff, row_ptr, cursor);
  fill_csr<<<eblk, 256, 0, stream>>>(esrc, edst, ew, cursor, col, wv);

  const int gemm_blocks = (N_NODES / 16) * 2;  // 12500
  const int agg_blocks = (N_NODES + 3) / 4;    // 25000

  const float* in = x;
  for (int l = 0; l < N_LAYERS; ++l) {
    float* o = (l == N_LAYERS - 1) ? out : act_buf;
    gemm128<<<gemm_blocks, 256, 0, stream>>>(in, W + (size_t)l * DIM * DIM,
                                             h_buf);
    aggregate<<<agg_blocks, 256, 0, stream>>>(h_buf, row_ptr, col, wv,
                                              b + (size_t)l * DIM, o);
    in = o;
  }
}

// Round 3
// 602.541 us; speedup vs baseline: 13.8848x; 1.6002x over previous
//
#include <hip/hip_runtime.h>
#include <hip/hip_bf16.h>

#define N_NODES 100000
#define N_EDGES 1600000
#define DIM 128
#define N_LAYERS 3

#define SCAN_T 1024
#define NB ((N_NODES + SCAN_T - 1) / SCAN_T)  // 98

typedef __attribute__((ext_vector_type(8))) short bf16x8;
typedef __attribute__((ext_vector_type(4))) float f32x4;

__device__ __forceinline__ ushort f2bf(float f) {
  union { float f; uint u; } v;
  v.f = f;
  uint r = v.u + 0x7fffu + ((v.u >> 16) & 1u);  // RNE
  return (ushort)(r >> 16);
}
__device__ __forceinline__ float u2f(uint u) {
  union { uint u; float f; } v;
  v.u = u;
  return v.f;
}

// ---------------------------------------------------------------------------
// Wt[l][n][k] (bf16) = W[l][k][n]  — 3 x 128 x 128
// ---------------------------------------------------------------------------
__global__ __launch_bounds__(256) void prep_wt(const float* __restrict__ W,
                                               ushort* __restrict__ Wt) {
  const int i = blockIdx.x * 256 + threadIdx.x;  // < 3*128*128
  const int l = i >> 14, rem = i & 16383;
  const int k = rem >> 7, n = rem & 127;
  Wt[(size_t)l * 16384 + n * DIM + k] = f2bf(W[(size_t)l * 16384 + k * DIM + n]);
}

// ---------------------------------------------------------------------------
// MFMA GEMM: H(bf16) = X @ W, X fp32 or bf16.  4 waves/block, 16 rows/wave.
// A frag: row = lane&15, k = (lane>>4)*8 + i   (K chunks of 32)
// B frag: col = lane&15, k = (lane>>4)*8 + i   (from Wt[col][k], global/L1)
// C frag: reg j -> row = (lane>>4)*4 + j, col = lane&15
// ---------------------------------------------------------------------------
__global__ __launch_bounds__(256) void gemm_f32in(const float* __restrict__ X,
                                                  const ushort* __restrict__ Wt,
                                                  ushort* __restrict__ H) {
  const int wid = threadIdx.x >> 6, lane = threadIdx.x & 63;
  const int row0 = blockIdx.x * 64 + wid * 16;
  if (row0 >= N_NODES) return;
  const int r = lane & 15, kg = lane >> 4;
  const size_t row = row0 + r;

  bf16x8 a[4];
#pragma unroll
  for (int c = 0; c < 4; ++c) {
    const float4 u = *(const float4*)&X[row * DIM + c * 32 + kg * 8];
    const float4 v = *(const float4*)&X[row * DIM + c * 32 + kg * 8 + 4];
    a[c][0] = (short)f2bf(u.x); a[c][1] = (short)f2bf(u.y);
    a[c][2] = (short)f2bf(u.z); a[c][3] = (short)f2bf(u.w);
    a[c][4] = (short)f2bf(v.x); a[c][5] = (short)f2bf(v.y);
    a[c][6] = (short)f2bf(v.z); a[c][7] = (short)f2bf(v.w);
  }
#pragma unroll
  for (int t = 0; t < 8; ++t) {
    f32x4 acc = {0.f, 0.f, 0.f, 0.f};
#pragma unroll
    for (int c = 0; c < 4; ++c) {
      const bf16x8 b = *(const bf16x8*)&Wt[(size_t)(t * 16 + r) * DIM + c * 32 + kg * 8];
      acc = __builtin_amdgcn_mfma_f32_16x16x32_bf16(a[c], b, acc, 0, 0, 0);
    }
#pragma unroll
    for (int j = 0; j < 4; ++j)
      H[(size_t)(row0 + kg * 4 + j) * DIM + t * 16 + r] = f2bf(acc[j]);
  }
}

__global__ __launch_bounds__(256) void gemm_bf16in(const ushort* __restrict__ X,
                                                   const ushort* __restrict__ Wt,
                                                   ushort* __restrict__ H) {
  const int wid = threadIdx.x >> 6, lane = threadIdx.x & 63;
  const int row0 = blockIdx.x * 64 + wid * 16;
  if (row0 >= N_NODES) return;
  const int r = lane & 15, kg = lane >> 4;
  const size_t row = row0 + r;

  bf16x8 a[4];
#pragma unroll
  for (int c = 0; c < 4; ++c)
    a[c] = *(const bf16x8*)&X[row * DIM + c * 32 + kg * 8];
#pragma unroll
  for (int t = 0; t < 8; ++t) {
    f32x4 acc = {0.f, 0.f, 0.f, 0.f};
#pragma unroll
    for (int c = 0; c < 4; ++c) {
      const bf16x8 b = *(const bf16x8*)&Wt[(size_t)(t * 16 + r) * DIM + c * 32 + kg * 8];
      acc = __builtin_amdgcn_mfma_f32_16x16x32_bf16(a[c], b, acc, 0, 0, 0);
    }
#pragma unroll
    for (int j = 0; j < 4; ++j)
      H[(size_t)(row0 + kg * 4 + j) * DIM + t * 16 + r] = f2bf(acc[j]);
  }
}

// ---------------------------------------------------------------------------
// CSR build: histogram -> exclusive scan -> cursor fill
// ---------------------------------------------------------------------------
__global__ __launch_bounds__(256) void zero_cnt(int* __restrict__ cnt) {
  const int i = blockIdx.x * 256 + threadIdx.x;
  if (i < N_NODES) cnt[i] = 0;
}

__global__ __launch_bounds__(256) void hist_dst(const int* __restrict__ dst,
                                                int* __restrict__ cnt) {
  const int e = blockIdx.x * 256 + threadIdx.x;
  if (e < N_EDGES) atomicAdd(&cnt[dst[e]], 1);
}

__global__ __launch_bounds__(SCAN_T) void scan_reduce(
    const int* __restrict__ cnt, int* __restrict__ bsum) {
  __shared__ int sh[SCAN_T];
  const int i = blockIdx.x * SCAN_T + threadIdx.x;
  sh[threadIdx.x] = (i < N_NODES) ? cnt[i] : 0;
  __syncthreads();
  for (int off = SCAN_T / 2; off > 0; off >>= 1) {
    if (threadIdx.x < off) sh[threadIdx.x] += sh[threadIdx.x + off];
    __syncthreads();
  }
  if (threadIdx.x == 0) bsum[blockIdx.x] = sh[0];
}

__global__ __launch_bounds__(128) void scan_bsum(const int* __restrict__ bsum,
                                                 int* __restrict__ boff) {
  __shared__ int sh[128];
  const int t = threadIdx.x;
  const int v = (t < NB) ? bsum[t] : 0;
  sh[t] = v;
  __syncthreads();
  for (int off = 1; off < 128; off <<= 1) {
    int a = (t >= off) ? sh[t - off] : 0;
    __syncthreads();
    sh[t] += a;
    __syncthreads();
  }
  if (t < NB) boff[t] = sh[t] - v;  // exclusive
}

__global__ __launch_bounds__(SCAN_T) void scan_final(
    const int* __restrict__ cnt, const int* __restrict__ boff,
    int* __restrict__ row_ptr, int* __restrict__ cursor) {
  __shared__ int sh[SCAN_T];
  const int i = blockIdx.x * SCAN_T + threadIdx.x;
  const int v = (i < N_NODES) ? cnt[i] : 0;
  sh[threadIdx.x] = v;
  __syncthreads();
  for (int off = 1; off < SCAN_T; off <<= 1) {
    int a = (threadIdx.x >= off) ? sh[threadIdx.x - off] : 0;
    __syncthreads();
    sh[threadIdx.x] += a;
    __syncthreads();
  }
  const int ex = sh[threadIdx.x] - v + boff[blockIdx.x];
  if (i < N_NODES) {
    row_ptr[i] = ex;
    cursor[i] = ex;
  }
  if (i == 0) row_ptr[N_NODES] = N_EDGES;
}

__global__ __launch_bounds__(256) void fill_csr(
    const int* __restrict__ src, const int* __restrict__ dst,
    const float* __restrict__ ew, int* __restrict__ cursor,
    int* __restrict__ col, float* __restrict__ wv) {
  const int e = blockIdx.x * 256 + threadIdx.x;
  if (e >= N_EDGES) return;
  const int d = dst[e];
  const int pos = atomicAdd(&cursor[d], 1);
  col[pos] = src[e];
  wv[pos] = ew[e];
}

// ---------------------------------------------------------------------------
// aggregate: out[n][:] = relu( sum_{e} H[col[e]][:]*wv[e] + bias )
// one 64-lane wave per node, 2 bf16 cols per lane, 2-edge unroll.
// OUTF32=1 -> write fp32 (final layer), else bf16 activations.
// ---------------------------------------------------------------------------
template <int OUTF32>
__global__ __launch_bounds__(256) void aggregate_b(
    const ushort* __restrict__ H, const int* __restrict__ row_ptr,
    const int* __restrict__ col, const float* __restrict__ wv,
    const float* __restrict__ bias, float* __restrict__ outf,
    ushort* __restrict__ outb) {
  const int node = blockIdx.x * 4 + (threadIdx.x >> 6);
  const int lane = threadIdx.x & 63;
  if (node >= N_NODES) return;
  int i = row_ptr[node];
  const int end = row_ptr[node + 1];
  float ax = 0.f, ay = 0.f;
  for (; i + 2 <= end; i += 2) {
    const int s0 = col[i], s1 = col[i + 1];
    const float w0 = wv[i], w1 = wv[i + 1];
    const uint u0 = *(const uint*)&H[(size_t)s0 * DIM + lane * 2];
    const uint u1 = *(const uint*)&H[(size_t)s1 * DIM + lane * 2];
    ax += w0 * u2f(u0 << 16);
    ay += w0 * u2f(u0 & 0xffff0000u);
    ax += w1 * u2f(u1 << 16);
    ay += w1 * u2f(u1 & 0xffff0000u);
  }
  if (i < end) {
    const int s0 = col[i];
    const float w0 = wv[i];
    const uint u0 = *(const uint*)&H[(size_t)s0 * DIM + lane * 2];
    ax += w0 * u2f(u0 << 16);
    ay += w0 * u2f(u0 & 0xffff0000u);
  }
  ax = fmaxf(ax + bias[lane * 2], 0.f);
  ay = fmaxf(ay + bias[lane * 2 + 1], 0.f);
  if (OUTF32) {
    float2 o = {ax, ay};
    *(float2*)&outf[(size_t)node * DIM + lane * 2] = o;
  } else {
    const uint p = (uint)f2bf(ax) | ((uint)f2bf(ay) << 16);
    *(uint*)&outb[(size_t)node * DIM + lane * 2] = p;
  }
}

extern "C" void kernel_launch(void* const* d_in, const int* in_sizes, int n_in,
                              void* d_out, int out_size, void* d_ws,
                              size_t ws_size, hipStream_t stream) {
  const float* x = (const float*)d_in[0];
  const int* esrc = (const int*)d_in[1];
  const int* edst = (const int*)d_in[2];
  const float* ew = (const float*)d_in[3];
  const float* W = (const float*)d_in[4];
  const float* b = (const float*)d_in[5];
  float* out = (float*)d_out;

  // workspace layout
  ushort* h_buf = (ushort*)d_ws;                        // [N*D] bf16
  ushort* act_buf = h_buf + (size_t)N_NODES * DIM;      // [N*D] bf16
  ushort* Wt = act_buf + (size_t)N_NODES * DIM;         // [3*128*128] bf16
  int* col = (int*)(Wt + 3 * DIM * DIM);                // [E]
  float* wv = (float*)(col + N_EDGES);                  // [E]
  int* cnt = (int*)(wv + N_EDGES);                      // [N]
  int* row_ptr = cnt + N_NODES;                         // [N+1]
  int* cursor = row_ptr + N_NODES + 1;                  // [N]
  int* bsum = cursor + N_NODES;                         // [NB]
  int* boff = bsum + NB;                                // [NB]

  const int nblk = (N_NODES + 255) / 256;  // 391
  const int eblk = (N_EDGES + 255) / 256;  // 6250

  prep_wt<<<3 * DIM * DIM / 256, 256, 0, stream>>>(W, Wt);

  // ---- CSR build (once, reused by all 3 layers) ----
  zero_cnt<<<nblk, 256, 0, stream>>>(cnt);
  hist_dst<<<eblk, 256, 0, stream>>>(edst, cnt);
  scan_reduce<<<NB, SCAN_T, 0, stream>>>(cnt, bsum);
  scan_bsum<<<1, 128, 0, stream>>>(bsum, boff);
  scan_final<<<NB, SCAN_T, 0, stream>>>(cnt, boff, row_ptr, cursor);
  fill_csr<<<eblk, 256, 0, stream>>>(esrc, edst, ew, cursor, col, wv);

  const int gemm_blocks = (N_NODES + 63) / 64;  // 1563
  const int agg_blocks = (N_NODES + 3) / 4;     // 25000

  // layer 0: fp32 x -> h ; aggregate -> act (bf16)
  gemm_f32in<<<gemm_blocks, 256, 0, stream>>>(x, Wt, h_buf);
  aggregate_b<0><<<agg_blocks, 256, 0, stream>>>(h_buf, row_ptr, col, wv, b,
                                                 nullptr, act_buf);
  // layer 1: act -> h ; aggregate -> act
  gemm_bf16in<<<gemm_blocks, 256, 0, stream>>>(act_buf, Wt + DIM * DIM, h_buf);
  aggregate_b<0><<<agg_blocks, 256, 0, stream>>>(h_buf, row_ptr, col, wv,
                                                 b + DIM, nullptr, act_buf);
  // layer 2: act -> h ; aggregate -> out (fp32)
  gemm_bf16in<<<gemm_blocks, 256, 0, stream>>>(act_buf, Wt + 2 * DIM * DIM,
                                               h_buf);
  aggregate_b<1><<<agg_blocks, 256, 0, stream>>>(h_buf, row_ptr, col, wv,
                                                 b + 2 * DIM, out, nullptr);
}

// Round 4
// 529.081 us; speedup vs baseline: 15.8127x; 1.1388x over previous
//
#include <hip/hip_runtime.h>
#include <hip/hip_bf16.h>

#define N_NODES 100000
#define N_EDGES 1600000
#define DIM 128
#define N_LAYERS 3

#define SCAN_T 1024
#define NB ((N_NODES + SCAN_T - 1) / SCAN_T)  // 98

typedef __attribute__((ext_vector_type(8))) short bf16x8;
typedef __attribute__((ext_vector_type(4))) float f32x4;

__device__ __forceinline__ ushort f2bf(float f) {
  union { float f; uint u; } v;
  v.f = f;
  uint r = v.u + 0x7fffu + ((v.u >> 16) & 1u);  // RNE
  return (ushort)(r >> 16);
}
__device__ __forceinline__ float u2f(uint u) {
  union { uint u; float f; } v;
  v.u = u;
  return v.f;
}

// ---------------------------------------------------------------------------
// Wt[l][n][k] (bf16) = W[l][k][n]  — 3 x 128 x 128
// ---------------------------------------------------------------------------
__global__ __launch_bounds__(256) void prep_wt(const float* __restrict__ W,
                                               ushort* __restrict__ Wt) {
  const int i = blockIdx.x * 256 + threadIdx.x;  // < 3*128*128
  const int l = i >> 14, rem = i & 16383;
  const int k = rem >> 7, n = rem & 127;
  Wt[(size_t)l * 16384 + n * DIM + k] = f2bf(W[(size_t)l * 16384 + k * DIM + n]);
}

// ---------------------------------------------------------------------------
// MFMA GEMM: H(bf16) = X @ W, X fp32 or bf16.  4 waves/block, 16 rows/wave.
// ---------------------------------------------------------------------------
__global__ __launch_bounds__(256) void gemm_f32in(const float* __restrict__ X,
                                                  const ushort* __restrict__ Wt,
                                                  ushort* __restrict__ H) {
  const int wid = threadIdx.x >> 6, lane = threadIdx.x & 63;
  const int row0 = blockIdx.x * 64 + wid * 16;
  if (row0 >= N_NODES) return;
  const int r = lane & 15, kg = lane >> 4;
  const size_t row = row0 + r;

  bf16x8 a[4];
#pragma unroll
  for (int c = 0; c < 4; ++c) {
    const float4 u = *(const float4*)&X[row * DIM + c * 32 + kg * 8];
    const float4 v = *(const float4*)&X[row * DIM + c * 32 + kg * 8 + 4];
    a[c][0] = (short)f2bf(u.x); a[c][1] = (short)f2bf(u.y);
    a[c][2] = (short)f2bf(u.z); a[c][3] = (short)f2bf(u.w);
    a[c][4] = (short)f2bf(v.x); a[c][5] = (short)f2bf(v.y);
    a[c][6] = (short)f2bf(v.z); a[c][7] = (short)f2bf(v.w);
  }
#pragma unroll
  for (int t = 0; t < 8; ++t) {
    f32x4 acc = {0.f, 0.f, 0.f, 0.f};
#pragma unroll
    for (int c = 0; c < 4; ++c) {
      const bf16x8 b = *(const bf16x8*)&Wt[(size_t)(t * 16 + r) * DIM + c * 32 + kg * 8];
      acc = __builtin_amdgcn_mfma_f32_16x16x32_bf16(a[c], b, acc, 0, 0, 0);
    }
#pragma unroll
    for (int j = 0; j < 4; ++j)
      H[(size_t)(row0 + kg * 4 + j) * DIM + t * 16 + r] = f2bf(acc[j]);
  }
}

__global__ __launch_bounds__(256) void gemm_bf16in(const ushort* __restrict__ X,
                                                   const ushort* __restrict__ Wt,
                                                   ushort* __restrict__ H) {
  const int wid = threadIdx.x >> 6, lane = threadIdx.x & 63;
  const int row0 = blockIdx.x * 64 + wid * 16;
  if (row0 >= N_NODES) return;
  const int r = lane & 15, kg = lane >> 4;
  const size_t row = row0 + r;

  bf16x8 a[4];
#pragma unroll
  for (int c = 0; c < 4; ++c)
    a[c] = *(const bf16x8*)&X[row * DIM + c * 32 + kg * 8];
#pragma unroll
  for (int t = 0; t < 8; ++t) {
    f32x4 acc = {0.f, 0.f, 0.f, 0.f};
#pragma unroll
    for (int c = 0; c < 4; ++c) {
      const bf16x8 b = *(const bf16x8*)&Wt[(size_t)(t * 16 + r) * DIM + c * 32 + kg * 8];
      acc = __builtin_amdgcn_mfma_f32_16x16x32_bf16(a[c], b, acc, 0, 0, 0);
    }
#pragma unroll
    for (int j = 0; j < 4; ++j)
      H[(size_t)(row0 + kg * 4 + j) * DIM + t * 16 + r] = f2bf(acc[j]);
  }
}

// ---------------------------------------------------------------------------
// CSR build: histogram -> exclusive scan -> cursor fill (packed uint2 payload)
// ---------------------------------------------------------------------------
__global__ __launch_bounds__(256) void zero_cnt(int* __restrict__ cnt) {
  const int i = blockIdx.x * 256 + threadIdx.x;
  if (i < N_NODES) cnt[i] = 0;
}

__global__ __launch_bounds__(256) void hist_dst(const int* __restrict__ dst,
                                                int* __restrict__ cnt) {
  const int e = blockIdx.x * 256 + threadIdx.x;
  if (e < N_EDGES) atomicAdd(&cnt[dst[e]], 1);
}

__global__ __launch_bounds__(SCAN_T) void scan_reduce(
    const int* __restrict__ cnt, int* __restrict__ bsum) {
  __shared__ int sh[SCAN_T];
  const int i = blockIdx.x * SCAN_T + threadIdx.x;
  sh[threadIdx.x] = (i < N_NODES) ? cnt[i] : 0;
  __syncthreads();
  for (int off = SCAN_T / 2; off > 0; off >>= 1) {
    if (threadIdx.x < off) sh[threadIdx.x] += sh[threadIdx.x + off];
    __syncthreads();
  }
  if (threadIdx.x == 0) bsum[blockIdx.x] = sh[0];
}

__global__ __launch_bounds__(128) void scan_bsum(const int* __restrict__ bsum,
                                                 int* __restrict__ boff) {
  __shared__ int sh[128];
  const int t = threadIdx.x;
  const int v = (t < NB) ? bsum[t] : 0;
  sh[t] = v;
  __syncthreads();
  for (int off = 1; off < 128; off <<= 1) {
    int a = (t >= off) ? sh[t - off] : 0;
    __syncthreads();
    sh[t] += a;
    __syncthreads();
  }
  if (t < NB) boff[t] = sh[t] - v;  // exclusive
}

__global__ __launch_bounds__(SCAN_T) void scan_final(
    const int* __restrict__ cnt, const int* __restrict__ boff,
    int* __restrict__ row_ptr, int* __restrict__ cursor) {
  __shared__ int sh[SCAN_T];
  const int i = blockIdx.x * SCAN_T + threadIdx.x;
  const int v = (i < N_NODES) ? cnt[i] : 0;
  sh[threadIdx.x] = v;
  __syncthreads();
  for (int off = 1; off < SCAN_T; off <<= 1) {
    int a = (threadIdx.x >= off) ? sh[threadIdx.x - off] : 0;
    __syncthreads();
    sh[threadIdx.x] += a;
    __syncthreads();
  }
  const int ex = sh[threadIdx.x] - v + boff[blockIdx.x];
  if (i < N_NODES) {
    row_ptr[i] = ex;
    cursor[i] = ex;
  }
  if (i == 0) row_ptr[N_NODES] = N_EDGES;
}

__global__ __launch_bounds__(256) void fill_csr(
    const int* __restrict__ src, const int* __restrict__ dst,
    const float* __restrict__ ew, int* __restrict__ cursor,
    uint2* __restrict__ ecsr) {
  const int e = blockIdx.x * 256 + threadIdx.x;
  if (e >= N_EDGES) return;
  const int d = dst[e];
  const int pos = atomicAdd(&cursor[d], 1);
  uint2 p;
  p.x = (uint)src[e];
  p.y = __float_as_uint(ew[e]);
  ecsr[pos] = p;  // single 8B store per edge
}

// ---------------------------------------------------------------------------
// aggregate: out[n][:] = relu( sum_{e} H[col[e]][:]*wv[e] + bias )
// one 64-lane wave per node, 2 bf16 cols per lane, 4-edge unroll.
// ---------------------------------------------------------------------------
template <int OUTF32>
__global__ __launch_bounds__(256) void aggregate_b(
    const ushort* __restrict__ H, const int* __restrict__ row_ptr,
    const uint2* __restrict__ ecsr, const float* __restrict__ bias,
    float* __restrict__ outf, ushort* __restrict__ outb) {
  const int node = blockIdx.x * 4 + (threadIdx.x >> 6);
  const int lane = threadIdx.x & 63;
  if (node >= N_NODES) return;
  int i = row_ptr[node];
  const int end = row_ptr[node + 1];
  float ax = 0.f, ay = 0.f;
  for (; i + 4 <= end; i += 4) {
    const uint2 e0 = ecsr[i], e1 = ecsr[i + 1], e2 = ecsr[i + 2],
                e3 = ecsr[i + 3];
    const uint h0 = *(const uint*)&H[(size_t)e0.x * DIM + lane * 2];
    const uint h1 = *(const uint*)&H[(size_t)e1.x * DIM + lane * 2];
    const uint h2 = *(const uint*)&H[(size_t)e2.x * DIM + lane * 2];
    const uint h3 = *(const uint*)&H[(size_t)e3.x * DIM + lane * 2];
    const float w0 = u2f(e0.y), w1 = u2f(e1.y), w2 = u2f(e2.y), w3 = u2f(e3.y);
    ax += w0 * u2f(h0 << 16);
    ay += w0 * u2f(h0 & 0xffff0000u);
    ax += w1 * u2f(h1 << 16);
    ay += w1 * u2f(h1 & 0xffff0000u);
    ax += w2 * u2f(h2 << 16);
    ay += w2 * u2f(h2 & 0xffff0000u);
    ax += w3 * u2f(h3 << 16);
    ay += w3 * u2f(h3 & 0xffff0000u);
  }
  for (; i < end; ++i) {
    const uint2 e0 = ecsr[i];
    const float w0 = u2f(e0.y);
    const uint h0 = *(const uint*)&H[(size_t)e0.x * DIM + lane * 2];
    ax += w0 * u2f(h0 << 16);
    ay += w0 * u2f(h0 & 0xffff0000u);
  }
  ax = fmaxf(ax + bias[lane * 2], 0.f);
  ay = fmaxf(ay + bias[lane * 2 + 1], 0.f);
  if (OUTF32) {
    float2 o = {ax, ay};
    *(float2*)&outf[(size_t)node * DIM + lane * 2] = o;
  } else {
    const uint p = (uint)f2bf(ax) | ((uint)f2bf(ay) << 16);
    *(uint*)&outb[(size_t)node * DIM + lane * 2] = p;
  }
}

extern "C" void kernel_launch(void* const* d_in, const int* in_sizes, int n_in,
                              void* d_out, int out_size, void* d_ws,
                              size_t ws_size, hipStream_t stream) {
  const float* x = (const float*)d_in[0];
  const int* esrc = (const int*)d_in[1];
  const int* edst = (const int*)d_in[2];
  const float* ew = (const float*)d_in[3];
  const float* W = (const float*)d_in[4];
  const float* b = (const float*)d_in[5];
  float* out = (float*)d_out;

  // workspace layout
  ushort* h_buf = (ushort*)d_ws;                        // [N*D] bf16
  ushort* act_buf = h_buf + (size_t)N_NODES * DIM;      // [N*D] bf16
  ushort* Wt = act_buf + (size_t)N_NODES * DIM;         // [3*128*128] bf16
  uint2* ecsr = (uint2*)(Wt + 3 * DIM * DIM);           // [E] packed (src,w)
  int* cnt = (int*)(ecsr + N_EDGES);                    // [N]
  int* row_ptr = cnt + N_NODES;                         // [N+1]
  int* cursor = row_ptr + N_NODES + 1;                  // [N]
  int* bsum = cursor + N_NODES;                         // [NB]
  int* boff = bsum + NB;                                // [NB]

  const int nblk = (N_NODES + 255) / 256;  // 391
  const int eblk = (N_EDGES + 255) / 256;  // 6250

  prep_wt<<<3 * DIM * DIM / 256, 256, 0, stream>>>(W, Wt);

  // ---- CSR build (once, reused by all 3 layers) ----
  zero_cnt<<<nblk, 256, 0, stream>>>(cnt);
  hist_dst<<<eblk, 256, 0, stream>>>(edst, cnt);
  scan_reduce<<<NB, SCAN_T, 0, stream>>>(cnt, bsum);
  scan_bsum<<<1, 128, 0, stream>>>(bsum, boff);
  scan_final<<<NB, SCAN_T, 0, stream>>>(cnt, boff, row_ptr, cursor);
  fill_csr<<<eblk, 256, 0, stream>>>(esrc, edst, ew, cursor, ecsr);

  const int gemm_blocks = (N_NODES + 63) / 64;  // 1563
  const int agg_blocks = (N_NODES + 3) / 4;     // 25000

  // layer 0: fp32 x -> h ; aggregate -> act (bf16)
  gemm_f32in<<<gemm_blocks, 256, 0, stream>>>(x, Wt, h_buf);
  aggregate_b<0><<<agg_blocks, 256, 0, stream>>>(h_buf, row_ptr, ecsr, b,
                                                 nullptr, act_buf);
  // layer 1: act -> h ; aggregate -> act
  gemm_bf16in<<<gemm_blocks, 256, 0, stream>>>(act_buf, Wt + DIM * DIM, h_buf);
  aggregate_b<0><<<agg_blocks, 256, 0, stream>>>(h_buf, row_ptr, ecsr, b + DIM,
                                                 nullptr, act_buf);
  // layer 2: act -> h ; aggregate -> out (fp32)
  gemm_bf16in<<<gemm_blocks, 256, 0, stream>>>(act_buf, Wt + 2 * DIM * DIM,
                                               h_buf);
  aggregate_b<1><<<agg_blocks, 256, 0, stream>>>(h_buf, row_ptr, ecsr,
                                                 b + 2 * DIM, out, nullptr);
}

// Round 5
// 497.182 us; speedup vs baseline: 16.8272x; 1.0642x over previous
//
#include <hip/hip_runtime.h>
#include <hip/hip_bf16.h>

#define N_NODES 100000
#define N_EDGES 1600000
#define DIM 128
#define N_LAYERS 3

#define SCAN_T 1024
#define NB ((N_NODES + SCAN_T - 1) / SCAN_T)  // 98

// ranged fill_csr
#define NRANGE 8
#define RANGE_NODES (N_NODES / NRANGE)  // 12500
#define FILL_CHUNK 2048
#define FILL_BPR ((N_EDGES + FILL_CHUNK - 1) / FILL_CHUNK)  // 782

typedef __attribute__((ext_vector_type(8))) short bf16x8;
typedef __attribute__((ext_vector_type(4))) float f32x4;

__device__ __forceinline__ ushort f2bf(float f) {
  union { float f; uint u; } v;
  v.f = f;
  uint r = v.u + 0x7fffu + ((v.u >> 16) & 1u);  // RNE
  return (ushort)(r >> 16);
}
__device__ __forceinline__ float u2f(uint u) {
  union { uint u; float f; } v;
  v.u = u;
  return v.f;
}

// ---------------------------------------------------------------------------
// Wt[l][n][k] (bf16) = W[l][k][n]  — 3 x 128 x 128
// ---------------------------------------------------------------------------
__global__ __launch_bounds__(256) void prep_wt(const float* __restrict__ W,
                                               ushort* __restrict__ Wt) {
  const int i = blockIdx.x * 256 + threadIdx.x;  // < 3*128*128
  const int l = i >> 14, rem = i & 16383;
  const int k = rem >> 7, n = rem & 127;
  Wt[(size_t)l * 16384 + n * DIM + k] = f2bf(W[(size_t)l * 16384 + k * DIM + n]);
}

// ---------------------------------------------------------------------------
// MFMA GEMM: H(bf16) = X @ W, X fp32 or bf16.  4 waves/block, 16 rows/wave.
// ---------------------------------------------------------------------------
__global__ __launch_bounds__(256) void gemm_f32in(const float* __restrict__ X,
                                                  const ushort* __restrict__ Wt,
                                                  ushort* __restrict__ H) {
  const int wid = threadIdx.x >> 6, lane = threadIdx.x & 63;
  const int row0 = blockIdx.x * 64 + wid * 16;
  if (row0 >= N_NODES) return;
  const int r = lane & 15, kg = lane >> 4;
  const size_t row = row0 + r;

  bf16x8 a[4];
#pragma unroll
  for (int c = 0; c < 4; ++c) {
    const float4 u = *(const float4*)&X[row * DIM + c * 32 + kg * 8];
    const float4 v = *(const float4*)&X[row * DIM + c * 32 + kg * 8 + 4];
    a[c][0] = (short)f2bf(u.x); a[c][1] = (short)f2bf(u.y);
    a[c][2] = (short)f2bf(u.z); a[c][3] = (short)f2bf(u.w);
    a[c][4] = (short)f2bf(v.x); a[c][5] = (short)f2bf(v.y);
    a[c][6] = (short)f2bf(v.z); a[c][7] = (short)f2bf(v.w);
  }
#pragma unroll
  for (int t = 0; t < 8; ++t) {
    f32x4 acc = {0.f, 0.f, 0.f, 0.f};
#pragma unroll
    for (int c = 0; c < 4; ++c) {
      const bf16x8 b = *(const bf16x8*)&Wt[(size_t)(t * 16 + r) * DIM + c * 32 + kg * 8];
      acc = __builtin_amdgcn_mfma_f32_16x16x32_bf16(a[c], b, acc, 0, 0, 0);
    }
#pragma unroll
    for (int j = 0; j < 4; ++j)
      H[(size_t)(row0 + kg * 4 + j) * DIM + t * 16 + r] = f2bf(acc[j]);
  }
}

__global__ __launch_bounds__(256) void gemm_bf16in(const ushort* __restrict__ X,
                                                   const ushort* __restrict__ Wt,
                                                   ushort* __restrict__ H) {
  const int wid = threadIdx.x >> 6, lane = threadIdx.x & 63;
  const int row0 = blockIdx.x * 64 + wid * 16;
  if (row0 >= N_NODES) return;
  const int r = lane & 15, kg = lane >> 4;
  const size_t row = row0 + r;

  bf16x8 a[4];
#pragma unroll
  for (int c = 0; c < 4; ++c)
    a[c] = *(const bf16x8*)&X[row * DIM + c * 32 + kg * 8];
#pragma unroll
  for (int t = 0; t < 8; ++t) {
    f32x4 acc = {0.f, 0.f, 0.f, 0.f};
#pragma unroll
    for (int c = 0; c < 4; ++c) {
      const bf16x8 b = *(const bf16x8*)&Wt[(size_t)(t * 16 + r) * DIM + c * 32 + kg * 8];
      acc = __builtin_amdgcn_mfma_f32_16x16x32_bf16(a[c], b, acc, 0, 0, 0);
    }
#pragma unroll
    for (int j = 0; j < 4; ++j)
      H[(size_t)(row0 + kg * 4 + j) * DIM + t * 16 + r] = f2bf(acc[j]);
  }
}

// ---------------------------------------------------------------------------
// CSR build: histogram -> exclusive scan -> ranged cursor fill
// ---------------------------------------------------------------------------
__global__ __launch_bounds__(256) void zero_cnt(int* __restrict__ cnt) {
  const int i = blockIdx.x * 256 + threadIdx.x;
  if (i < N_NODES) cnt[i] = 0;
}

__global__ __launch_bounds__(256) void hist_dst(const int* __restrict__ dst,
                                                int* __restrict__ cnt) {
  const int e0 = (blockIdx.x * 256 + threadIdx.x) * 4;
  if (e0 >= N_EDGES) return;
  const int4 d4 = *(const int4*)&dst[e0];
  atomicAdd(&cnt[d4.x], 1);
  atomicAdd(&cnt[d4.y], 1);
  atomicAdd(&cnt[d4.z], 1);
  atomicAdd(&cnt[d4.w], 1);
}

__global__ __launch_bounds__(SCAN_T) void scan_reduce(
    const int* __restrict__ cnt, int* __restrict__ bsum) {
  __shared__ int sh[SCAN_T];
  const int i = blockIdx.x * SCAN_T + threadIdx.x;
  sh[threadIdx.x] = (i < N_NODES) ? cnt[i] : 0;
  __syncthreads();
  for (int off = SCAN_T / 2; off > 0; off >>= 1) {
    if (threadIdx.x < off) sh[threadIdx.x] += sh[threadIdx.x + off];
    __syncthreads();
  }
  if (threadIdx.x == 0) bsum[blockIdx.x] = sh[0];
}

__global__ __launch_bounds__(128) void scan_bsum(const int* __restrict__ bsum,
                                                 int* __restrict__ boff) {
  __shared__ int sh[128];
  const int t = threadIdx.x;
  const int v = (t < NB) ? bsum[t] : 0;
  sh[t] = v;
  __syncthreads();
  for (int off = 1; off < 128; off <<= 1) {
    int a = (t >= off) ? sh[t - off] : 0;
    __syncthreads();
    sh[t] += a;
    __syncthreads();
  }
  if (t < NB) boff[t] = sh[t] - v;  // exclusive
}

__global__ __launch_bounds__(SCAN_T) void scan_final(
    const int* __restrict__ cnt, const int* __restrict__ boff,
    int* __restrict__ row_ptr, int* __restrict__ cursor) {
  __shared__ int sh[SCAN_T];
  const int i = blockIdx.x * SCAN_T + threadIdx.x;
  const int v = (i < N_NODES) ? cnt[i] : 0;
  sh[threadIdx.x] = v;
  __syncthreads();
  for (int off = 1; off < SCAN_T; off <<= 1) {
    int a = (threadIdx.x >= off) ? sh[threadIdx.x - off] : 0;
    __syncthreads();
    sh[threadIdx.x] += a;
    __syncthreads();
  }
  const int ex = sh[threadIdx.x] - v + boff[blockIdx.x];
  if (i < N_NODES) {
    row_ptr[i] = ex;
    cursor[i] = ex;
  }
  if (i == 0) row_ptr[N_NODES] = N_EDGES;
}

// Each block owns dst range [lo,hi) and scans one edge chunk; only in-range
// edges are written. Scatter footprint per range = ~1.6 MB -> L2-resident.
__global__ __launch_bounds__(256) void fill_csr_ranged(
    const int* __restrict__ src, const int* __restrict__ dst,
    const float* __restrict__ ew, int* __restrict__ cursor,
    uint2* __restrict__ ecsr) {
  const int range = blockIdx.x / FILL_BPR;
  const int chunk = blockIdx.x % FILL_BPR;
  const int lo = range * RANGE_NODES;
  const int hi = lo + RANGE_NODES;
  const int base = chunk * FILL_CHUNK;
#pragma unroll
  for (int it = 0; it < FILL_CHUNK / (256 * 4); ++it) {
    const int e0 = base + (it * 256 + threadIdx.x) * 4;
    if (e0 >= N_EDGES) continue;
    const int4 d4 = *(const int4*)&dst[e0];
#pragma unroll
    for (int j = 0; j < 4; ++j) {
      const int d = (j == 0) ? d4.x : (j == 1) ? d4.y : (j == 2) ? d4.z : d4.w;
      if (d >= lo && d < hi) {
        const int e = e0 + j;
        const int pos = atomicAdd(&cursor[d], 1);
        uint2 p;
        p.x = (uint)src[e];
        p.y = __float_as_uint(ew[e]);
        ecsr[pos] = p;
      }
    }
  }
}

// ---------------------------------------------------------------------------
// aggregate: out[n][:] = relu( sum_{e} H[col[e]][:]*wv[e] + bias )
// one 64-lane wave per node, 2 bf16 cols per lane, 8-edge unroll.
// ---------------------------------------------------------------------------
template <int OUTF32>
__global__ __launch_bounds__(256) void aggregate_b(
    const ushort* __restrict__ H, const int* __restrict__ row_ptr,
    const uint2* __restrict__ ecsr, const float* __restrict__ bias,
    float* __restrict__ outf, ushort* __restrict__ outb) {
  const int node = blockIdx.x * 4 + (threadIdx.x >> 6);
  const int lane = threadIdx.x & 63;
  if (node >= N_NODES) return;
  int i = row_ptr[node];
  const int end = row_ptr[node + 1];
  float ax = 0.f, ay = 0.f;
  for (; i + 8 <= end; i += 8) {
    uint2 e[8];
    uint h[8];
#pragma unroll
    for (int j = 0; j < 8; ++j) e[j] = ecsr[i + j];
#pragma unroll
    for (int j = 0; j < 8; ++j)
      h[j] = *(const uint*)&H[(size_t)e[j].x * DIM + lane * 2];
#pragma unroll
    for (int j = 0; j < 8; ++j) {
      const float w = u2f(e[j].y);
      ax += w * u2f(h[j] << 16);
      ay += w * u2f(h[j] & 0xffff0000u);
    }
  }
  for (; i < end; ++i) {
    const uint2 e0 = ecsr[i];
    const float w0 = u2f(e0.y);
    const uint h0 = *(const uint*)&H[(size_t)e0.x * DIM + lane * 2];
    ax += w0 * u2f(h0 << 16);
    ay += w0 * u2f(h0 & 0xffff0000u);
  }
  ax = fmaxf(ax + bias[lane * 2], 0.f);
  ay = fmaxf(ay + bias[lane * 2 + 1], 0.f);
  if (OUTF32) {
    float2 o = {ax, ay};
    *(float2*)&outf[(size_t)node * DIM + lane * 2] = o;
  } else {
    const uint p = (uint)f2bf(ax) | ((uint)f2bf(ay) << 16);
    *(uint*)&outb[(size_t)node * DIM + lane * 2] = p;
  }
}

extern "C" void kernel_launch(void* const* d_in, const int* in_sizes, int n_in,
                              void* d_out, int out_size, void* d_ws,
                              size_t ws_size, hipStream_t stream) {
  const float* x = (const float*)d_in[0];
  const int* esrc = (const int*)d_in[1];
  const int* edst = (const int*)d_in[2];
  const float* ew = (const float*)d_in[3];
  const float* W = (const float*)d_in[4];
  const float* b = (const float*)d_in[5];
  float* out = (float*)d_out;

  // workspace layout
  ushort* h_buf = (ushort*)d_ws;                        // [N*D] bf16
  ushort* act_buf = h_buf + (size_t)N_NODES * DIM;      // [N*D] bf16
  ushort* Wt = act_buf + (size_t)N_NODES * DIM;         // [3*128*128] bf16
  uint2* ecsr = (uint2*)(Wt + 3 * DIM * DIM);           // [E] packed (src,w)
  int* cnt = (int*)(ecsr + N_EDGES);                    // [N]
  int* row_ptr = cnt + N_NODES;                         // [N+1]
  int* cursor = row_ptr + N_NODES + 1;                  // [N]
  int* bsum = cursor + N_NODES;                         // [NB]
  int* boff = bsum + NB;                                // [NB]

  const int nblk = (N_NODES + 255) / 256;        // 391
  const int eblk4 = (N_EDGES / 4 + 255) / 256;   // 1563

  prep_wt<<<3 * DIM * DIM / 256, 256, 0, stream>>>(W, Wt);

  // ---- CSR build (once, reused by all 3 layers) ----
  zero_cnt<<<nblk, 256, 0, stream>>>(cnt);
  hist_dst<<<eblk4, 256, 0, stream>>>(edst, cnt);
  scan_reduce<<<NB, SCAN_T, 0, stream>>>(cnt, bsum);
  scan_bsum<<<1, 128, 0, stream>>>(bsum, boff);
  scan_final<<<NB, SCAN_T, 0, stream>>>(cnt, boff, row_ptr, cursor);
  fill_csr_ranged<<<NRANGE * FILL_BPR, 256, 0, stream>>>(esrc, edst, ew, cursor,
                                                         ecsr);

  const int gemm_blocks = (N_NODES + 63) / 64;  // 1563
  const int agg_blocks = (N_NODES + 3) / 4;     // 25000

  // layer 0: fp32 x -> h ; aggregate -> act (bf16)
  gemm_f32in<<<gemm_blocks, 256, 0, stream>>>(x, Wt, h_buf);
  aggregate_b<0><<<agg_blocks, 256, 0, stream>>>(h_buf, row_ptr, ecsr, b,
                                                 nullptr, act_buf);
  // layer 1: act -> h ; aggregate -> act
  gemm_bf16in<<<gemm_blocks, 256, 0, stream>>>(act_buf, Wt + DIM * DIM, h_buf);
  aggregate_b<0><<<agg_blocks, 256, 0, stream>>>(h_buf, row_ptr, ecsr, b + DIM,
                                                 nullptr, act_buf);
  // layer 2: act -> h ; aggregate -> out (fp32)
  gemm_bf16in<<<gemm_blocks, 256, 0, stream>>>(act_buf, Wt + 2 * DIM * DIM,
                                               h_buf);
  aggregate_b<1><<<agg_blocks, 256, 0, stream>>>(h_buf, row_ptr, ecsr,
                                                 b + 2 * DIM, out, nullptr);
}

// Round 6
// 489.145 us; speedup vs baseline: 17.1037x; 1.0164x over previous
//
#include <hip/hip_runtime.h>
#include <hip/hip_bf16.h>

#define N_NODES 100000
#define N_EDGES 1600000
#define DIM 128
#define N_LAYERS 3

#define SCAN_T 1024
#define NB ((N_NODES + SCAN_T - 1) / SCAN_T)  // 98

// ranged fill_csr: range = blockIdx % NRANGE  -> all blocks of a range land
// on the same XCD (round-robin dispatch), so the range's CSR region lives in
// ONE XCD's L2 and lines fill completely before writeback.
#define NRANGE 8
#define RANGE_NODES (N_NODES / NRANGE)  // 12500
#define FILL_CHUNK 2048
#define FILL_BPR ((N_EDGES + FILL_CHUNK - 1) / FILL_CHUNK)  // 782

typedef __attribute__((ext_vector_type(8))) short bf16x8;
typedef __attribute__((ext_vector_type(4))) float f32x4;

__device__ __forceinline__ ushort f2bf(float f) {
  union { float f; uint u; } v;
  v.f = f;
  uint r = v.u + 0x7fffu + ((v.u >> 16) & 1u);  // RNE
  return (ushort)(r >> 16);
}
__device__ __forceinline__ float u2f(uint u) {
  union { uint u; float f; } v;
  v.u = u;
  return v.f;
}

// ---------------------------------------------------------------------------
// Wt[l][n][k] (bf16) = W[l][k][n]  — 3 x 128 x 128
// ---------------------------------------------------------------------------
__global__ __launch_bounds__(256) void prep_wt(const float* __restrict__ W,
                                               ushort* __restrict__ Wt) {
  const int i = blockIdx.x * 256 + threadIdx.x;  // < 3*128*128
  const int l = i >> 14, rem = i & 16383;
  const int k = rem >> 7, n = rem & 127;
  Wt[(size_t)l * 16384 + n * DIM + k] = f2bf(W[(size_t)l * 16384 + k * DIM + n]);
}

// ---------------------------------------------------------------------------
// MFMA GEMM: H(bf16) = X @ W, X fp32 or bf16.  4 waves/block, 16 rows/wave.
// ---------------------------------------------------------------------------
__global__ __launch_bounds__(256) void gemm_f32in(const float* __restrict__ X,
                                                  const ushort* __restrict__ Wt,
                                                  ushort* __restrict__ H) {
  const int wid = threadIdx.x >> 6, lane = threadIdx.x & 63;
  const int row0 = blockIdx.x * 64 + wid * 16;
  if (row0 >= N_NODES) return;
  const int r = lane & 15, kg = lane >> 4;
  const size_t row = row0 + r;

  bf16x8 a[4];
#pragma unroll
  for (int c = 0; c < 4; ++c) {
    const float4 u = *(const float4*)&X[row * DIM + c * 32 + kg * 8];
    const float4 v = *(const float4*)&X[row * DIM + c * 32 + kg * 8 + 4];
    a[c][0] = (short)f2bf(u.x); a[c][1] = (short)f2bf(u.y);
    a[c][2] = (short)f2bf(u.z); a[c][3] = (short)f2bf(u.w);
    a[c][4] = (short)f2bf(v.x); a[c][5] = (short)f2bf(v.y);
    a[c][6] = (short)f2bf(v.z); a[c][7] = (short)f2bf(v.w);
  }
#pragma unroll
  for (int t = 0; t < 8; ++t) {
    f32x4 acc = {0.f, 0.f, 0.f, 0.f};
#pragma unroll
    for (int c = 0; c < 4; ++c) {
      const bf16x8 b = *(const bf16x8*)&Wt[(size_t)(t * 16 + r) * DIM + c * 32 + kg * 8];
      acc = __builtin_amdgcn_mfma_f32_16x16x32_bf16(a[c], b, acc, 0, 0, 0);
    }
#pragma unroll
    for (int j = 0; j < 4; ++j)
      H[(size_t)(row0 + kg * 4 + j) * DIM + t * 16 + r] = f2bf(acc[j]);
  }
}

__global__ __launch_bounds__(256) void gemm_bf16in(const ushort* __restrict__ X,
                                                   const ushort* __restrict__ Wt,
                                                   ushort* __restrict__ H) {
  const int wid = threadIdx.x >> 6, lane = threadIdx.x & 63;
  const int row0 = blockIdx.x * 64 + wid * 16;
  if (row0 >= N_NODES) return;
  const int r = lane & 15, kg = lane >> 4;
  const size_t row = row0 + r;

  bf16x8 a[4];
#pragma unroll
  for (int c = 0; c < 4; ++c)
    a[c] = *(const bf16x8*)&X[row * DIM + c * 32 + kg * 8];
#pragma unroll
  for (int t = 0; t < 8; ++t) {
    f32x4 acc = {0.f, 0.f, 0.f, 0.f};
#pragma unroll
    for (int c = 0; c < 4; ++c) {
      const bf16x8 b = *(const bf16x8*)&Wt[(size_t)(t * 16 + r) * DIM + c * 32 + kg * 8];
      acc = __builtin_amdgcn_mfma_f32_16x16x32_bf16(a[c], b, acc, 0, 0, 0);
    }
#pragma unroll
    for (int j = 0; j < 4; ++j)
      H[(size_t)(row0 + kg * 4 + j) * DIM + t * 16 + r] = f2bf(acc[j]);
  }
}

// ---------------------------------------------------------------------------
// CSR build: histogram -> exclusive scan -> XCD-owned ranged cursor fill
// ---------------------------------------------------------------------------
__global__ __launch_bounds__(256) void zero_cnt(int* __restrict__ cnt) {
  const int i = blockIdx.x * 256 + threadIdx.x;
  if (i < N_NODES) cnt[i] = 0;
}

__global__ __launch_bounds__(256) void hist_dst(const int* __restrict__ dst,
                                                int* __restrict__ cnt) {
  const int e0 = (blockIdx.x * 256 + threadIdx.x) * 4;
  if (e0 >= N_EDGES) return;
  const int4 d4 = *(const int4*)&dst[e0];
  atomicAdd(&cnt[d4.x], 1);
  atomicAdd(&cnt[d4.y], 1);
  atomicAdd(&cnt[d4.z], 1);
  atomicAdd(&cnt[d4.w], 1);
}

__global__ __launch_bounds__(SCAN_T) void scan_reduce(
    const int* __restrict__ cnt, int* __restrict__ bsum) {
  __shared__ int sh[SCAN_T];
  const int i = blockIdx.x * SCAN_T + threadIdx.x;
  sh[threadIdx.x] = (i < N_NODES) ? cnt[i] : 0;
  __syncthreads();
  for (int off = SCAN_T / 2; off > 0; off >>= 1) {
    if (threadIdx.x < off) sh[threadIdx.x] += sh[threadIdx.x + off];
    __syncthreads();
  }
  if (threadIdx.x == 0) bsum[blockIdx.x] = sh[0];
}

__global__ __launch_bounds__(128) void scan_bsum(const int* __restrict__ bsum,
                                                 int* __restrict__ boff) {
  __shared__ int sh[128];
  const int t = threadIdx.x;
  const int v = (t < NB) ? bsum[t] : 0;
  sh[t] = v;
  __syncthreads();
  for (int off = 1; off < 128; off <<= 1) {
    int a = (t >= off) ? sh[t - off] : 0;
    __syncthreads();
    sh[t] += a;
    __syncthreads();
  }
  if (t < NB) boff[t] = sh[t] - v;  // exclusive
}

__global__ __launch_bounds__(SCAN_T) void scan_final(
    const int* __restrict__ cnt, const int* __restrict__ boff,
    int* __restrict__ row_ptr, int* __restrict__ cursor) {
  __shared__ int sh[SCAN_T];
  const int i = blockIdx.x * SCAN_T + threadIdx.x;
  const int v = (i < N_NODES) ? cnt[i] : 0;
  sh[threadIdx.x] = v;
  __syncthreads();
  for (int off = 1; off < SCAN_T; off <<= 1) {
    int a = (threadIdx.x >= off) ? sh[threadIdx.x - off] : 0;
    __syncthreads();
    sh[threadIdx.x] += a;
    __syncthreads();
  }
  const int ex = sh[threadIdx.x] - v + boff[blockIdx.x];
  if (i < N_NODES) {
    row_ptr[i] = ex;
    cursor[i] = ex;
  }
  if (i == 0) row_ptr[N_NODES] = N_EDGES;
}

// range = blockIdx % NRANGE: with round-robin block->XCD dispatch, each range's
// blocks all land on one XCD, so its ~1.6MB CSR region is written by a single
// L2 -> lines fill fully, writeback once.
__global__ __launch_bounds__(256) void fill_csr_ranged(
    const int* __restrict__ src, const int* __restrict__ dst,
    const float* __restrict__ ew, int* __restrict__ cursor,
    uint2* __restrict__ ecsr) {
  const int range = blockIdx.x % NRANGE;
  const int chunk = blockIdx.x / NRANGE;
  const int lo = range * RANGE_NODES;
  const int hi = lo + RANGE_NODES;
  const int base = chunk * FILL_CHUNK;
#pragma unroll
  for (int it = 0; it < FILL_CHUNK / (256 * 4); ++it) {
    const int e0 = base + (it * 256 + threadIdx.x) * 4;
    if (e0 >= N_EDGES) continue;
    const int4 d4 = *(const int4*)&dst[e0];
#pragma unroll
    for (int j = 0; j < 4; ++j) {
      const int d = (j == 0) ? d4.x : (j == 1) ? d4.y : (j == 2) ? d4.z : d4.w;
      if (d >= lo && d < hi) {
        const int e = e0 + j;
        const int pos = atomicAdd(&cursor[d], 1);
        uint2 p;
        p.x = (uint)src[e];
        p.y = __float_as_uint(ew[e]);
        ecsr[pos] = p;
      }
    }
  }
}

// ---------------------------------------------------------------------------
// aggregate: out[n][:] = relu( sum_{e} H[col[e]][:]*wv[e] + bias )
// one 64-lane wave per node, 2 bf16 cols per lane, 8-edge unroll.
// ---------------------------------------------------------------------------
template <int OUTF32>
__global__ __launch_bounds__(256) void aggregate_b(
    const ushort* __restrict__ H, const int* __restrict__ row_ptr,
    const uint2* __restrict__ ecsr, const float* __restrict__ bias,
    float* __restrict__ outf, ushort* __restrict__ outb) {
  const int node = blockIdx.x * 4 + (threadIdx.x >> 6);
  const int lane = threadIdx.x & 63;
  if (node >= N_NODES) return;
  int i = row_ptr[node];
  const int end = row_ptr[node + 1];
  float ax = 0.f, ay = 0.f;
  for (; i + 8 <= end; i += 8) {
    uint2 e[8];
    uint h[8];
#pragma unroll
    for (int j = 0; j < 8; ++j) e[j] = ecsr[i + j];
#pragma unroll
    for (int j = 0; j < 8; ++j)
      h[j] = *(const uint*)&H[(size_t)e[j].x * DIM + lane * 2];
#pragma unroll
    for (int j = 0; j < 8; ++j) {
      const float w = u2f(e[j].y);
      ax += w * u2f(h[j] << 16);
      ay += w * u2f(h[j] & 0xffff0000u);
    }
  }
  for (; i < end; ++i) {
    const uint2 e0 = ecsr[i];
    const float w0 = u2f(e0.y);
    const uint h0 = *(const uint*)&H[(size_t)e0.x * DIM + lane * 2];
    ax += w0 * u2f(h0 << 16);
    ay += w0 * u2f(h0 & 0xffff0000u);
  }
  ax = fmaxf(ax + bias[lane * 2], 0.f);
  ay = fmaxf(ay + bias[lane * 2 + 1], 0.f);
  if (OUTF32) {
    float2 o = {ax, ay};
    *(float2*)&outf[(size_t)node * DIM + lane * 2] = o;
  } else {
    const uint p = (uint)f2bf(ax) | ((uint)f2bf(ay) << 16);
    *(uint*)&outb[(size_t)node * DIM + lane * 2] = p;
  }
}

extern "C" void kernel_launch(void* const* d_in, const int* in_sizes, int n_in,
                              void* d_out, int out_size, void* d_ws,
                              size_t ws_size, hipStream_t stream) {
  const float* x = (const float*)d_in[0];
  const int* esrc = (const int*)d_in[1];
  const int* edst = (const int*)d_in[2];
  const float* ew = (const float*)d_in[3];
  const float* W = (const float*)d_in[4];
  const float* b = (const float*)d_in[5];
  float* out = (float*)d_out;

  // workspace layout
  ushort* h_buf = (ushort*)d_ws;                        // [N*D] bf16
  ushort* act_buf = h_buf + (size_t)N_NODES * DIM;      // [N*D] bf16
  ushort* Wt = act_buf + (size_t)N_NODES * DIM;         // [3*128*128] bf16
  uint2* ecsr = (uint2*)(Wt + 3 * DIM * DIM);           // [E] packed (src,w)
  int* cnt = (int*)(ecsr + N_EDGES);                    // [N]
  int* row_ptr = cnt + N_NODES;                         // [N+1]
  int* cursor = row_ptr + N_NODES + 1;                  // [N]
  int* bsum = cursor + N_NODES;                         // [NB]
  int* boff = bsum + NB;                                // [NB]

  const int nblk = (N_NODES + 255) / 256;        // 391
  const int eblk4 = (N_EDGES / 4 + 255) / 256;   // 1563

  prep_wt<<<3 * DIM * DIM / 256, 256, 0, stream>>>(W, Wt);

  // ---- CSR build (once, reused by all 3 layers) ----
  zero_cnt<<<nblk, 256, 0, stream>>>(cnt);
  hist_dst<<<eblk4, 256, 0, stream>>>(edst, cnt);
  scan_reduce<<<NB, SCAN_T, 0, stream>>>(cnt, bsum);
  scan_bsum<<<1, 128, 0, stream>>>(bsum, boff);
  scan_final<<<NB, SCAN_T, 0, stream>>>(cnt, boff, row_ptr, cursor);
  fill_csr_ranged<<<NRANGE * FILL_BPR, 256, 0, stream>>>(esrc, edst, ew, cursor,
                                                         ecsr);

  const int gemm_blocks = (N_NODES + 63) / 64;  // 1563
  const int agg_blocks = (N_NODES + 3) / 4;     // 25000

  // layer 0: fp32 x -> h ; aggregate -> act (bf16)
  gemm_f32in<<<gemm_blocks, 256, 0, stream>>>(x, Wt, h_buf);
  aggregate_b<0><<<agg_blocks, 256, 0, stream>>>(h_buf, row_ptr, ecsr, b,
                                                 nullptr, act_buf);
  // layer 1: act -> h ; aggregate -> act
  gemm_bf16in<<<gemm_blocks, 256, 0, stream>>>(act_buf, Wt + DIM * DIM, h_buf);
  aggregate_b<0><<<agg_blocks, 256, 0, stream>>>(h_buf, row_ptr, ecsr, b + DIM,
                                                 nullptr, act_buf);
  // layer 2: act -> h ; aggregate -> out (fp32)
  gemm_bf16in<<<gemm_blocks, 256, 0, stream>>>(act_buf, Wt + 2 * DIM * DIM,
                                               h_buf);
  aggregate_b<1><<<agg_blocks, 256, 0, stream>>>(h_buf, row_ptr, ecsr,
                                                 b + 2 * DIM, out, nullptr);
}

// Round 7
// 457.142 us; speedup vs baseline: 18.3011x; 1.0700x over previous
//
#include <hip/hip_runtime.h>
#include <hip/hip_bf16.h>

#define N_NODES 100000
#define N_EDGES 1600000
#define DIM 128
#define N_LAYERS 3

#define SCAN_T 1024
#define NB ((N_NODES + SCAN_T - 1) / SCAN_T)  // 98

// ranged fill_csr: range = blockIdx % NRANGE  -> all blocks of a range land
// on the same XCD (round-robin dispatch), so the range's CSR region lives in
// ONE XCD's L2 and lines fill completely before writeback.
#define NRANGE 8
#define RANGE_NODES (N_NODES / NRANGE)  // 12500
#define FILL_CHUNK 2048
#define FILL_BPR ((N_EDGES + FILL_CHUNK - 1) / FILL_CHUNK)  // 782

typedef __attribute__((ext_vector_type(8))) short bf16x8;
typedef __attribute__((ext_vector_type(4))) float f32x4;

__device__ __forceinline__ ushort f2bf(float f) {
  union { float f; uint u; } v;
  v.f = f;
  uint r = v.u + 0x7fffu + ((v.u >> 16) & 1u);  // RNE
  return (ushort)(r >> 16);
}
__device__ __forceinline__ float u2f(uint u) {
  union { uint u; float f; } v;
  v.u = u;
  return v.f;
}

// ---------------------------------------------------------------------------
// Wt[l][n][k] (bf16) = W[l][k][n]  — 3 x 128 x 128
// ---------------------------------------------------------------------------
__global__ __launch_bounds__(256) void prep_wt(const float* __restrict__ W,
                                               ushort* __restrict__ Wt) {
  const int i = blockIdx.x * 256 + threadIdx.x;  // < 3*128*128
  const int l = i >> 14, rem = i & 16383;
  const int k = rem >> 7, n = rem & 127;
  Wt[(size_t)l * 16384 + n * DIM + k] = f2bf(W[(size_t)l * 16384 + k * DIM + n]);
}

// ---------------------------------------------------------------------------
// MFMA GEMM: H(bf16) = X @ W, X fp32 or bf16.  4 waves/block, 16 rows/wave.
// ---------------------------------------------------------------------------
__global__ __launch_bounds__(256) void gemm_f32in(const float* __restrict__ X,
                                                  const ushort* __restrict__ Wt,
                                                  ushort* __restrict__ H) {
  const int wid = threadIdx.x >> 6, lane = threadIdx.x & 63;
  const int row0 = blockIdx.x * 64 + wid * 16;
  if (row0 >= N_NODES) return;
  const int r = lane & 15, kg = lane >> 4;
  const size_t row = row0 + r;

  bf16x8 a[4];
#pragma unroll
  for (int c = 0; c < 4; ++c) {
    const float4 u = *(const float4*)&X[row * DIM + c * 32 + kg * 8];
    const float4 v = *(const float4*)&X[row * DIM + c * 32 + kg * 8 + 4];
    a[c][0] = (short)f2bf(u.x); a[c][1] = (short)f2bf(u.y);
    a[c][2] = (short)f2bf(u.z); a[c][3] = (short)f2bf(u.w);
    a[c][4] = (short)f2bf(v.x); a[c][5] = (short)f2bf(v.y);
    a[c][6] = (short)f2bf(v.z); a[c][7] = (short)f2bf(v.w);
  }
#pragma unroll
  for (int t = 0; t < 8; ++t) {
    f32x4 acc = {0.f, 0.f, 0.f, 0.f};
#pragma unroll
    for (int c = 0; c < 4; ++c) {
      const bf16x8 b = *(const bf16x8*)&Wt[(size_t)(t * 16 + r) * DIM + c * 32 + kg * 8];
      acc = __builtin_amdgcn_mfma_f32_16x16x32_bf16(a[c], b, acc, 0, 0, 0);
    }
#pragma unroll
    for (int j = 0; j < 4; ++j)
      H[(size_t)(row0 + kg * 4 + j) * DIM + t * 16 + r] = f2bf(acc[j]);
  }
}

__global__ __launch_bounds__(256) void gemm_bf16in(const ushort* __restrict__ X,
                                                   const ushort* __restrict__ Wt,
                                                   ushort* __restrict__ H) {
  const int wid = threadIdx.x >> 6, lane = threadIdx.x & 63;
  const int row0 = blockIdx.x * 64 + wid * 16;
  if (row0 >= N_NODES) return;
  const int r = lane & 15, kg = lane >> 4;
  const size_t row = row0 + r;

  bf16x8 a[4];
#pragma unroll
  for (int c = 0; c < 4; ++c)
    a[c] = *(const bf16x8*)&X[row * DIM + c * 32 + kg * 8];
#pragma unroll
  for (int t = 0; t < 8; ++t) {
    f32x4 acc = {0.f, 0.f, 0.f, 0.f};
#pragma unroll
    for (int c = 0; c < 4; ++c) {
      const bf16x8 b = *(const bf16x8*)&Wt[(size_t)(t * 16 + r) * DIM + c * 32 + kg * 8];
      acc = __builtin_amdgcn_mfma_f32_16x16x32_bf16(a[c], b, acc, 0, 0, 0);
    }
#pragma unroll
    for (int j = 0; j < 4; ++j)
      H[(size_t)(row0 + kg * 4 + j) * DIM + t * 16 + r] = f2bf(acc[j]);
  }
}

// ---------------------------------------------------------------------------
// CSR build: histogram -> exclusive scan -> XCD-owned ranged cursor fill
// ---------------------------------------------------------------------------
__global__ __launch_bounds__(256) void zero_cnt(int* __restrict__ cnt) {
  const int i = blockIdx.x * 256 + threadIdx.x;
  if (i < N_NODES) cnt[i] = 0;
}

__global__ __launch_bounds__(256) void hist_dst(const int* __restrict__ dst,
                                                int* __restrict__ cnt) {
  const int e0 = (blockIdx.x * 256 + threadIdx.x) * 4;
  if (e0 >= N_EDGES) return;
  const int4 d4 = *(const int4*)&dst[e0];
  atomicAdd(&cnt[d4.x], 1);
  atomicAdd(&cnt[d4.y], 1);
  atomicAdd(&cnt[d4.z], 1);
  atomicAdd(&cnt[d4.w], 1);
}

__global__ __launch_bounds__(SCAN_T) void scan_reduce(
    const int* __restrict__ cnt, int* __restrict__ bsum) {
  __shared__ int sh[SCAN_T];
  const int i = blockIdx.x * SCAN_T + threadIdx.x;
  sh[threadIdx.x] = (i < N_NODES) ? cnt[i] : 0;
  __syncthreads();
  for (int off = SCAN_T / 2; off > 0; off >>= 1) {
    if (threadIdx.x < off) sh[threadIdx.x] += sh[threadIdx.x + off];
    __syncthreads();
  }
  if (threadIdx.x == 0) bsum[blockIdx.x] = sh[0];
}

__global__ __launch_bounds__(128) void scan_bsum(const int* __restrict__ bsum,
                                                 int* __restrict__ boff) {
  __shared__ int sh[128];
  const int t = threadIdx.x;
  const int v = (t < NB) ? bsum[t] : 0;
  sh[t] = v;
  __syncthreads();
  for (int off = 1; off < 128; off <<= 1) {
    int a = (t >= off) ? sh[t - off] : 0;
    __syncthreads();
    sh[t] += a;
    __syncthreads();
  }
  if (t < NB) boff[t] = sh[t] - v;  // exclusive
}

__global__ __launch_bounds__(SCAN_T) void scan_final(
    const int* __restrict__ cnt, const int* __restrict__ boff,
    int* __restrict__ row_ptr, int* __restrict__ cursor) {
  __shared__ int sh[SCAN_T];
  const int i = blockIdx.x * SCAN_T + threadIdx.x;
  const int v = (i < N_NODES) ? cnt[i] : 0;
  sh[threadIdx.x] = v;
  __syncthreads();
  for (int off = 1; off < SCAN_T; off <<= 1) {
    int a = (threadIdx.x >= off) ? sh[threadIdx.x - off] : 0;
    __syncthreads();
    sh[threadIdx.x] += a;
    __syncthreads();
  }
  const int ex = sh[threadIdx.x] - v + boff[blockIdx.x];
  if (i < N_NODES) {
    row_ptr[i] = ex;
    cursor[i] = ex;
  }
  if (i == 0) row_ptr[N_NODES] = N_EDGES;
}

// range = blockIdx % NRANGE: with round-robin block->XCD dispatch, each range's
// blocks all land on one XCD, so its ~1.6MB CSR region is written by a single
// L2 -> lines fill fully, writeback once.
__global__ __launch_bounds__(256) void fill_csr_ranged(
    const int* __restrict__ src, const int* __restrict__ dst,
    const float* __restrict__ ew, int* __restrict__ cursor,
    uint2* __restrict__ ecsr) {
  const int range = blockIdx.x % NRANGE;
  const int chunk = blockIdx.x / NRANGE;
  const int lo = range * RANGE_NODES;
  const int hi = lo + RANGE_NODES;
  const int base = chunk * FILL_CHUNK;
#pragma unroll
  for (int it = 0; it < FILL_CHUNK / (256 * 4); ++it) {
    const int e0 = base + (it * 256 + threadIdx.x) * 4;
    if (e0 >= N_EDGES) continue;
    const int4 d4 = *(const int4*)&dst[e0];
#pragma unroll
    for (int j = 0; j < 4; ++j) {
      const int d = (j == 0) ? d4.x : (j == 1) ? d4.y : (j == 2) ? d4.z : d4.w;
      if (d >= lo && d < hi) {
        const int e = e0 + j;
        const int pos = atomicAdd(&cursor[d], 1);
        uint2 p;
        p.x = (uint)src[e];
        p.y = __float_as_uint(ew[e]);
        ecsr[pos] = p;
      }
    }
  }
}

// ---------------------------------------------------------------------------
// aggregate: out[n][:] = relu( sum_{e} H[col[e]][:]*wv[e] + bias )
// one HALF-wave (32 lanes) per node, 4 bf16 cols per lane (uint2 row loads),
// 8-edge unroll -> 16 gathers in flight per full wave.
// ---------------------------------------------------------------------------
template <int OUTF32>
__global__ __launch_bounds__(256) void aggregate_b(
    const ushort* __restrict__ H, const int* __restrict__ row_ptr,
    const uint2* __restrict__ ecsr, const float* __restrict__ bias,
    float* __restrict__ outf, ushort* __restrict__ outb) {
  const int node = blockIdx.x * 8 + (threadIdx.x >> 5);
  const int lane = threadIdx.x & 31;  // 32 lanes, 4 cols each
  if (node >= N_NODES) return;
  int i = row_ptr[node];
  const int end = row_ptr[node + 1];
  float a0 = 0.f, a1 = 0.f, a2 = 0.f, a3 = 0.f;
  for (; i + 8 <= end; i += 8) {
    uint2 e[8];
    uint2 h[8];
#pragma unroll
    for (int j = 0; j < 8; ++j) e[j] = ecsr[i + j];
#pragma unroll
    for (int j = 0; j < 8; ++j)
      h[j] = *(const uint2*)&H[(size_t)e[j].x * DIM + lane * 4];
#pragma unroll
    for (int j = 0; j < 8; ++j) {
      const float w = u2f(e[j].y);
      a0 += w * u2f(h[j].x << 16);
      a1 += w * u2f(h[j].x & 0xffff0000u);
      a2 += w * u2f(h[j].y << 16);
      a3 += w * u2f(h[j].y & 0xffff0000u);
    }
  }
  for (; i < end; ++i) {
    const uint2 e0 = ecsr[i];
    const float w = u2f(e0.y);
    const uint2 h0 = *(const uint2*)&H[(size_t)e0.x * DIM + lane * 4];
    a0 += w * u2f(h0.x << 16);
    a1 += w * u2f(h0.x & 0xffff0000u);
    a2 += w * u2f(h0.y << 16);
    a3 += w * u2f(h0.y & 0xffff0000u);
  }
  const float4 bv = *(const float4*)&bias[lane * 4];
  a0 = fmaxf(a0 + bv.x, 0.f);
  a1 = fmaxf(a1 + bv.y, 0.f);
  a2 = fmaxf(a2 + bv.z, 0.f);
  a3 = fmaxf(a3 + bv.w, 0.f);
  if (OUTF32) {
    float4 o = {a0, a1, a2, a3};
    *(float4*)&outf[(size_t)node * DIM + lane * 4] = o;
  } else {
    uint2 p;
    p.x = (uint)f2bf(a0) | ((uint)f2bf(a1) << 16);
    p.y = (uint)f2bf(a2) | ((uint)f2bf(a3) << 16);
    *(uint2*)&outb[(size_t)node * DIM + lane * 4] = p;
  }
}

extern "C" void kernel_launch(void* const* d_in, const int* in_sizes, int n_in,
                              void* d_out, int out_size, void* d_ws,
                              size_t ws_size, hipStream_t stream) {
  const float* x = (const float*)d_in[0];
  const int* esrc = (const int*)d_in[1];
  const int* edst = (const int*)d_in[2];
  const float* ew = (const float*)d_in[3];
  const float* W = (const float*)d_in[4];
  const float* b = (const float*)d_in[5];
  float* out = (float*)d_out;

  // workspace layout
  ushort* h_buf = (ushort*)d_ws;                        // [N*D] bf16
  ushort* act_buf = h_buf + (size_t)N_NODES * DIM;      // [N*D] bf16
  ushort* Wt = act_buf + (size_t)N_NODES * DIM;         // [3*128*128] bf16
  uint2* ecsr = (uint2*)(Wt + 3 * DIM * DIM);           // [E] packed (src,w)
  int* cnt = (int*)(ecsr + N_EDGES);                    // [N]
  int* row_ptr = cnt + N_NODES;                         // [N+1]
  int* cursor = row_ptr + N_NODES + 1;                  // [N]
  int* bsum = cursor + N_NODES;                         // [NB]
  int* boff = bsum + NB;                                // [NB]

  const int nblk = (N_NODES + 255) / 256;        // 391
  const int eblk4 = (N_EDGES / 4 + 255) / 256;   // 1563

  prep_wt<<<3 * DIM * DIM / 256, 256, 0, stream>>>(W, Wt);

  // ---- CSR build (once, reused by all 3 layers) ----
  zero_cnt<<<nblk, 256, 0, stream>>>(cnt);
  hist_dst<<<eblk4, 256, 0, stream>>>(edst, cnt);
  scan_reduce<<<NB, SCAN_T, 0, stream>>>(cnt, bsum);
  scan_bsum<<<1, 128, 0, stream>>>(bsum, boff);
  scan_final<<<NB, SCAN_T, 0, stream>>>(cnt, boff, row_ptr, cursor);
  fill_csr_ranged<<<NRANGE * FILL_BPR, 256, 0, stream>>>(esrc, edst, ew, cursor,
                                                         ecsr);

  const int gemm_blocks = (N_NODES + 63) / 64;  // 1563
  const int agg_blocks = (N_NODES + 7) / 8;     // 12500

  // layer 0: fp32 x -> h ; aggregate -> act (bf16)
  gemm_f32in<<<gemm_blocks, 256, 0, stream>>>(x, Wt, h_buf);
  aggregate_b<0><<<agg_blocks, 256, 0, stream>>>(h_buf, row_ptr, ecsr, b,
                                                 nullptr, act_buf);
  // layer 1: act -> h ; aggregate -> act
  gemm_bf16in<<<gemm_blocks, 256, 0, stream>>>(act_buf, Wt + DIM * DIM, h_buf);
  aggregate_b<0><<<agg_blocks, 256, 0, stream>>>(h_buf, row_ptr, ecsr, b + DIM,
                                                 nullptr, act_buf);
  // layer 2: act -> h ; aggregate -> out (fp32)
  gemm_bf16in<<<gemm_blocks, 256, 0, stream>>>(act_buf, Wt + 2 * DIM * DIM,
                                               h_buf);
  aggregate_b<1><<<agg_blocks, 256, 0, stream>>>(h_buf, row_ptr, ecsr,
                                                 b + 2 * DIM, out, nullptr);
}